// Round 3
// baseline (915.231 us; speedup 1.0000x reference)
//
#include <hip/hip_runtime.h>
#include <hip/hip_bf16.h>
#include <stdint.h>

typedef __attribute__((ext_vector_type(8))) short bf16x8;   // 8 bf16 = 4 VGPRs
typedef __attribute__((ext_vector_type(4))) float f32x4;

__device__ __forceinline__ unsigned short f2bf(float f) {
    unsigned u = __builtin_bit_cast(unsigned, f);
    u += 0x7FFF + ((u >> 16) & 1);        // RNE to bf16 (inputs are finite)
    return (unsigned short)(u >> 16);
}
__device__ __forceinline__ bf16x8 pack8(float4 a, float4 b) {
    bf16x8 r;
    r[0] = (short)f2bf(a.x); r[1] = (short)f2bf(a.y);
    r[2] = (short)f2bf(a.z); r[3] = (short)f2bf(a.w);
    r[4] = (short)f2bf(b.x); r[5] = (short)f2bf(b.y);
    r[6] = (short)f2bf(b.z); r[7] = (short)f2bf(b.w);
    return r;
}

// ---------------------------------------------------------------------------
// C[m,n] = sum_k A[m,k] * Bt[n,k], K=1024, K-contiguous operands.
// 128x128 block tile, 4 waves, 64x64 quadrant/wave, 4x4 x mfma 16x16x32 bf16.
// BK=64, conservative staging: global->VGPR (fp32->bf16 cvt) -> ds_write_b128.
// LDS rows padded to 72 shorts (row stride 144 B, 16B-aligned, <=2-way banks).
// MODE 0: A=x fp32, B=w_qkv fp32; epilogue relu+0.125 on q,k; bf16 q/k/v bufs.
// MODE 1: A=out2 bf16, B=w_proj fp32; epilogue +bias; fp32 out.
// ---------------------------------------------------------------------------
constexpr int LDSS = 72;

template<int MODE>
__global__ __launch_bounds__(256, 2)
void gemm_bt_kernel(const void* __restrict__ A,
                    const float* __restrict__ Bt,
                    __hip_bfloat16* __restrict__ o0,
                    __hip_bfloat16* __restrict__ o1,
                    __hip_bfloat16* __restrict__ o2,
                    float* __restrict__ outf,
                    const float* __restrict__ bias)
{
    constexpr int K = 1024;
    __shared__ __attribute__((aligned(16))) unsigned short As[128 * LDSS];
    __shared__ __attribute__((aligned(16))) unsigned short Bs[128 * LDSS];

    const int t   = threadIdx.x;
    const int bid = blockIdx.x;
    const int mt  = bid % 196;
    const int nt  = bid / 196;
    const long m0 = (long)mt * 128;
    const long n0 = (long)nt * 128;

    const int lane = t & 63;
    const int wv   = t >> 6;
    const int wm   = (wv & 1) << 6;
    const int wn   = (wv >> 1) << 6;
    const int fr   = lane & 15;
    const int qd   = lane >> 4;

    f32x4 acc[4][4] = {};

    const int lrow = t >> 3;          // 0..31
    const int lch  = t & 7;           // 0..7

    const float*          Bg  = Bt + (n0 + lrow) * K + lch * 8;
    const float*          Agf = (const float*)A          + (m0 + lrow) * K + lch * 8;
    const unsigned short* Agh = (const unsigned short*)A + (m0 + lrow) * K + lch * 8;

    for (int kb = 0; kb < K; kb += 64) {
        bf16x8 av[4], bv[4];
#pragma unroll
        for (int c = 0; c < 4; ++c) {
            const float* bp = Bg + (long)c * 32 * K + kb;
            bv[c] = pack8(*(const float4*)bp, *(const float4*)(bp + 4));
            if (MODE == 0) {
                const float* ap = Agf + (long)c * 32 * K + kb;
                av[c] = pack8(*(const float4*)ap, *(const float4*)(ap + 4));
            } else {
                av[c] = *(const bf16x8*)(Agh + (long)c * 32 * K + kb);
            }
        }
        __syncthreads();
#pragma unroll
        for (int c = 0; c < 4; ++c) {
            *(bf16x8*)(As + (c * 32 + lrow) * LDSS + lch * 8) = av[c];
            *(bf16x8*)(Bs + (c * 32 + lrow) * LDSS + lch * 8) = bv[c];
        }
        __syncthreads();
#pragma unroll
        for (int s = 0; s < 2; ++s) {
            bf16x8 af[4], bfv[4];
            const int ch = (s << 2) + qd;
#pragma unroll
            for (int i = 0; i < 4; ++i)
                af[i] = *(const bf16x8*)(As + (wm + i * 16 + fr) * LDSS + ch * 8);
#pragma unroll
            for (int j = 0; j < 4; ++j)
                bfv[j] = *(const bf16x8*)(Bs + (wn + j * 16 + fr) * LDSS + ch * 8);
#pragma unroll
            for (int i = 0; i < 4; ++i)
#pragma unroll
                for (int j = 0; j < 4; ++j)
                    acc[i][j] = __builtin_amdgcn_mfma_f32_16x16x32_bf16(
                        af[i], bfv[j], acc[i][j], 0, 0, 0);
        }
    }

    // C/D layout: col = lane&15 (=fr), row = qd*4 + reg
    if (MODE == 0) {
        const int which = nt >> 3;  // 0:q 1:k 2:v
        __hip_bfloat16* dst = (which == 0) ? o0 : (which == 1) ? o1 : o2;
        const int colbase = ((nt & 7) << 7) + wn;
        const bool act = (which < 2);
#pragma unroll
        for (int i = 0; i < 4; ++i) {
            const long mrow = m0 + wm + i * 16 + qd * 4;
#pragma unroll
            for (int r = 0; r < 4; ++r) {
                const long moff = (mrow + r) * 1024;
#pragma unroll
                for (int j = 0; j < 4; ++j) {
                    float v = acc[i][j][r];
                    if (act) v = fmaxf(v, 0.f) + 0.125f;
                    dst[moff + colbase + j * 16 + fr] = __float2bfloat16(v);
                }
            }
        }
    } else {
        const long nbase = n0 + wn;
#pragma unroll
        for (int i = 0; i < 4; ++i) {
            const long mrow = m0 + wm + i * 16 + qd * 4;
#pragma unroll
            for (int r = 0; r < 4; ++r) {
                const long moff = (mrow + r) * 1024;
#pragma unroll
                for (int j = 0; j < 4; ++j)
                    outf[moff + nbase + j * 16 + fr] =
                        acc[i][j][r] + bias[nbase + j * 16 + fr];
            }
        }
    }
}

// ---------------------------------------------------------------------------
// Phase 2: kv[bb,h,e,d] = sum_n k[n,e]*v[n,d]; ksum[bb,h,e] = sum_n k[n,e]
// n in [0,3136) split into 8 chunks of 392. Grid = 8(bb)*16(h)*8(s).
// ---------------------------------------------------------------------------
__global__ __launch_bounds__(256)
void kv_partial_kernel(const __hip_bfloat16* __restrict__ kbuf,
                       const __hip_bfloat16* __restrict__ vbuf,
                       float* __restrict__ kvp,    // [8][128][64][64]
                       float* __restrict__ ksump)  // [8][128][64]
{
    __shared__ float ks[8][64];
    __shared__ float vs[8][64];
    const int t  = threadIdx.x;
    const int b  = blockIdx.x;
    const int s  = b & 7;
    const int h  = (b >> 3) & 15;
    const int bb = b >> 7;
    const int e  = t >> 2;
    const int dbase = (t & 3) * 16;
    const long rowbase = (long)bb * 3136 + (long)s * 392;
    const int  colh = h * 64;

    float kvacc[16];
#pragma unroll
    for (int i = 0; i < 16; ++i) kvacc[i] = 0.f;
    float ksacc = 0.f;

    for (int g = 0; g < 49; ++g) {
        __syncthreads();
#pragma unroll
        for (int j = 0; j < 4; ++j) {
            const int idx = t + j * 256;
            const int r  = (idx >> 6) & 7;
            const int ee = idx & 63;
            const long grow = rowbase + g * 8 + r;
            if (idx < 512)
                ks[r][ee] = __bfloat162float(kbuf[grow * 1024 + colh + ee]);
            else
                vs[r][ee] = __bfloat162float(vbuf[grow * 1024 + colh + ee]);
        }
        __syncthreads();
#pragma unroll
        for (int r = 0; r < 8; ++r) {
            const float kk = ks[r][e];
            ksacc += kk;
#pragma unroll
            for (int d = 0; d < 16; ++d)
                kvacc[d] += kk * vs[r][dbase + d];
        }
    }
    const long base = ((long)(s * 128 + bb * 16 + h) * 64 + e) * 64 + dbase;
#pragma unroll
    for (int d = 0; d < 16; ++d) kvp[base + d] = kvacc[d];
    if ((t & 3) == 0) ksump[(s * 128 + bb * 16 + h) * 64 + e] = ksacc;
}

__global__ __launch_bounds__(256)
void reduce_kv_kernel(const float* __restrict__ kvp, const float* __restrict__ ksump,
                      float* __restrict__ kv, float* __restrict__ ksum)
{
    const int idx = blockIdx.x * 256 + threadIdx.x;
    if (idx < 128 * 64 * 64) {
        float a = 0.f;
#pragma unroll
        for (int s = 0; s < 8; ++s) a += kvp[(long)s * 128 * 64 * 64 + idx];
        kv[idx] = a;
    } else {
        const int j = idx - 128 * 64 * 64;
        if (j < 128 * 64) {
            float a = 0.f;
#pragma unroll
            for (int s = 0; s < 8; ++s) a += ksump[s * 128 * 64 + j];
            ksum[j] = a;
        }
    }
}

// ---------------------------------------------------------------------------
// Phase 3: out2[m, h*64+d] = z * sum_e q[m,e]*kv[bh,e,d],
//          z = 1/(sum_e q[m,e]*ksum[bh,e] + 1e-6).
// ---------------------------------------------------------------------------
__global__ __launch_bounds__(256)
void attn_out_kernel(const __hip_bfloat16* __restrict__ qbuf,
                     const float* __restrict__ kv,
                     const float* __restrict__ ksum,
                     __hip_bfloat16* __restrict__ out2)
{
    __shared__ float kvs[64][65];
    __shared__ float kss[64];
    __shared__ float qs[16][65];
    const int t   = threadIdx.x;
    const int bid = blockIdx.x;
    const int mc  = bid % 49;
    const int h   = (bid / 49) % 16;
    const int bb  = bid / (49 * 16);
    const long bh = bb * 16 + h;

#pragma unroll
    for (int j = 0; j < 16; ++j) {
        const int idx = t + j * 256;
        kvs[idx >> 6][idx & 63] = kv[bh * 4096 + idx];
    }
    if (t < 64) kss[t] = ksum[bh * 64 + t];

    const int r  = t >> 4;
    const int dl = (t & 15) * 4;
    const long mbase = (long)bb * 3136 + mc * 64;

    for (int cc = 0; cc < 4; ++cc) {
        __syncthreads();
#pragma unroll
        for (int j = 0; j < 4; ++j) {
            const int idx = t + j * 256;
            const int rr = idx >> 6;
            const int ee = idx & 63;
            const long m = mbase + cc * 16 + rr;
            qs[rr][ee] = __bfloat162float(qbuf[m * 1024 + h * 64 + ee]);
        }
        __syncthreads();
        float p = 0.f;
#pragma unroll
        for (int ii = 0; ii < 4; ++ii) p += qs[r][dl + ii] * kss[dl + ii];
#pragma unroll
        for (int off = 1; off < 16; off <<= 1) p += __shfl_xor(p, off, 64);
        p = fmaxf(p, 0.f);
        const float z = 1.f / (p + 1e-6f);

        float o0 = 0.f, o1 = 0.f, o2 = 0.f, o3 = 0.f;
#pragma unroll
        for (int e = 0; e < 64; ++e) {
            const float qv = qs[r][e];
            o0 += qv * kvs[e][dl + 0];
            o1 += qv * kvs[e][dl + 1];
            o2 += qv * kvs[e][dl + 2];
            o3 += qv * kvs[e][dl + 3];
        }
        const long m  = mbase + cc * 16 + r;
        const long ob = m * 1024 + h * 64 + dl;
        out2[ob + 0] = __float2bfloat16(o0 * z);
        out2[ob + 1] = __float2bfloat16(o1 * z);
        out2[ob + 2] = __float2bfloat16(o2 * z);
        out2[ob + 3] = __float2bfloat16(o3 * z);
    }
}

// ---------------------------------------------------------------------------
extern "C" void kernel_launch(void* const* d_in, const int* in_sizes, int n_in,
                              void* d_out, int out_size, void* d_ws, size_t ws_size,
                              hipStream_t stream)
{
    // Reference dtypes: all float32. num_frames int (unused; =16).
    const float* x      = (const float*)d_in[0];
    const float* w_qkv  = (const float*)d_in[1];
    const float* w_proj = (const float*)d_in[2];
    const float* b_proj = (const float*)d_in[3];
    float* out = (float*)d_out;

    const long M = 25088;  // 128*196
    char* ws = (char*)d_ws;
    size_t off = 0;
    auto alloc = [&](size_t bytes) {
        char* p = ws + off;
        off += (bytes + 255) & ~(size_t)255;
        return p;
    };
    // qbuf lives in d_out (25088*1024 bf16 = 51.4 MB; qbuf dead before the
    // final GEMM overwrites d_out). ws holds the rest (~122 MB).
    __hip_bfloat16* qbuf = (__hip_bfloat16*)d_out;
    __hip_bfloat16* kbuf = (__hip_bfloat16*)alloc(M * 1024 * 2);
    __hip_bfloat16* vbuf = (__hip_bfloat16*)alloc(M * 1024 * 2);
    float* kvp   = (float*)alloc((size_t)8 * 128 * 64 * 64 * 4);
    float* ksump = (float*)alloc((size_t)8 * 128 * 64 * 4);
    float* kvr   = (float*)alloc((size_t)128 * 64 * 64 * 4);
    float* ksumr = (float*)alloc((size_t)128 * 64 * 4);
    __hip_bfloat16* out2 = vbuf;  // v dead after phase 2: alias

    gemm_bt_kernel<0><<<196 * 24, 256, 0, stream>>>(
        x, w_qkv, qbuf, kbuf, vbuf, nullptr, nullptr);
    kv_partial_kernel<<<1024, 256, 0, stream>>>(kbuf, vbuf, kvp, ksump);
    reduce_kv_kernel<<<2080, 256, 0, stream>>>(kvp, ksump, kvr, ksumr);
    attn_out_kernel<<<8 * 16 * 49, 256, 0, stream>>>(qbuf, kvr, ksumr, out2);
    gemm_bt_kernel<1><<<196 * 8, 256, 0, stream>>>(
        out2, w_proj, nullptr, nullptr, nullptr, out, b_proj);
}

// Round 4
// 507.049 us; speedup vs baseline: 1.8050x; 1.8050x over previous
//
#include <hip/hip_runtime.h>
#include <hip/hip_bf16.h>
#include <stdint.h>

typedef __attribute__((ext_vector_type(8))) short bf16x8;   // 8 bf16 = 4 VGPRs
typedef __attribute__((ext_vector_type(4))) float f32x4;

__device__ __forceinline__ unsigned short f2bf(float f) {
    unsigned u = __builtin_bit_cast(unsigned, f);
    u += 0x7FFF + ((u >> 16) & 1);        // RNE (finite inputs)
    return (unsigned short)(u >> 16);
}
__device__ __forceinline__ float bf2f(unsigned short h) {
    return __builtin_bit_cast(float, (unsigned)h << 16);
}
__device__ __forceinline__ void load_lds16(const void* g, void* l) {
    __builtin_amdgcn_global_load_lds(
        (const __attribute__((address_space(1))) void*)g,
        (__attribute__((address_space(3))) void*)l, 16, 0, 0);
}

// ---------------------------------------------------------------------------
// fp32 -> bf16 bulk convert. n divisible by 2048; one thread = 8 elems.
// ---------------------------------------------------------------------------
__global__ __launch_bounds__(256)
void cvt_kernel(const float* __restrict__ src, unsigned short* __restrict__ dst)
{
    const long i = ((long)blockIdx.x * 256 + threadIdx.x) * 8;
    const float4 a = *(const float4*)(src + i);
    const float4 b = *(const float4*)(src + i + 4);
    bf16x8 r;
    r[0] = (short)f2bf(a.x); r[1] = (short)f2bf(a.y);
    r[2] = (short)f2bf(a.z); r[3] = (short)f2bf(a.w);
    r[4] = (short)f2bf(b.x); r[5] = (short)f2bf(b.y);
    r[6] = (short)f2bf(b.z); r[7] = (short)f2bf(b.w);
    *(bf16x8*)(dst + i) = r;
}

// ---------------------------------------------------------------------------
// C[m,n] = sum_k A[m,k]*Bt[n,k], K=1024, bf16 operands, K-contiguous.
// 128x128 tile, 4 waves, 64x64/wave, 4x4 x mfma 16x16x32. BK=64.
// Staging: global_load_lds width=16 (m97), XOR chunk-swizzle (chunk^=row&7)
// so frag ds_read_b128 is 2-way (free). Group-swizzled grid for L2 locality.
// MODE 0: epilogue relu+0.125 on q,k; scatter bf16 q/k/v. MODE 1: +bias, fp32.
// ---------------------------------------------------------------------------
template<int MODE>
__global__ __launch_bounds__(256, 2)
void gemm_bt_kernel(const unsigned short* __restrict__ A,
                    const unsigned short* __restrict__ Bt,
                    __hip_bfloat16* __restrict__ o0,
                    __hip_bfloat16* __restrict__ o1,
                    __hip_bfloat16* __restrict__ o2,
                    float* __restrict__ outf,
                    const float* __restrict__ bias)
{
    constexpr int K  = 1024;
    constexpr int NT = (MODE == 0) ? 24 : 8;
    __shared__ __attribute__((aligned(16))) unsigned short As[128 * 64];
    __shared__ __attribute__((aligned(16))) unsigned short Bs[128 * 64];

    // group-major swizzle: 8 m-tiles share B-tiles among co-resident blocks
    const int bid   = blockIdx.x;
    const int npg   = 8 * NT;
    const int group = bid / npg;
    const int rem   = bid - group * npg;
    const int gm    = (196 - group * 8 < 8) ? (196 - group * 8) : 8;
    const int mt    = group * 8 + rem % gm;
    const int nt    = rem / gm;
    const long m0 = (long)mt * 128;
    const long n0 = (long)nt * 128;

    const int t    = threadIdx.x;
    const int lane = t & 63;
    const int wv   = t >> 6;
    const int wm   = (wv & 1) << 6;
    const int wn   = (wv >> 1) << 6;
    const int fr   = lane & 15;
    const int qd   = lane >> 4;

    f32x4 acc[4][4] = {};

    // staging: thread t -> LDS row c*32 + (t>>3), LDS chunk t&7, which holds
    // global chunk (t&7)^(row&7). LDS dest = uniform base + lane*16.
    const int srow   = t >> 3;                  // 0..31
    const int gch    = (t & 7) ^ (srow & 7);
    const int wbytes = (t & 192) << 4;          // wave id * 1024

    const unsigned short* Ag = A  + (m0 + srow) * K + gch * 8;
    const unsigned short* Bg = Bt + (n0 + srow) * K + gch * 8;

    for (int kb = 0; kb < K; kb += 64) {
        __syncthreads();
#pragma unroll
        for (int c = 0; c < 4; ++c) {
            load_lds16(Ag + (long)c * 32 * K + kb, (char*)As + c * 4096 + wbytes);
            load_lds16(Bg + (long)c * 32 * K + kb, (char*)Bs + c * 4096 + wbytes);
        }
        __syncthreads();   // compiler emits s_waitcnt vmcnt(0) before barrier
#pragma unroll
        for (int s = 0; s < 2; ++s) {
            bf16x8 af[4], bfv[4];
            const int ch = ((s << 2) + qd) ^ (fr & 7);  // un-swizzle (row&7==fr&7)
#pragma unroll
            for (int i = 0; i < 4; ++i)
                af[i] = *(const bf16x8*)(As + (wm + i * 16 + fr) * 64 + ch * 8);
#pragma unroll
            for (int j = 0; j < 4; ++j)
                bfv[j] = *(const bf16x8*)(Bs + (wn + j * 16 + fr) * 64 + ch * 8);
#pragma unroll
            for (int i = 0; i < 4; ++i)
#pragma unroll
                for (int j = 0; j < 4; ++j)
                    acc[i][j] = __builtin_amdgcn_mfma_f32_16x16x32_bf16(
                        af[i], bfv[j], acc[i][j], 0, 0, 0);
        }
    }

    // C/D layout: col = fr, row = qd*4 + reg
    if (MODE == 0) {
        const int which = nt >> 3;  // 0:q 1:k 2:v
        __hip_bfloat16* dst = (which == 0) ? o0 : (which == 1) ? o1 : o2;
        const int colbase = ((nt & 7) << 7) + wn;
        const bool act = (which < 2);
#pragma unroll
        for (int i = 0; i < 4; ++i) {
            const long mrow = m0 + wm + i * 16 + qd * 4;
#pragma unroll
            for (int r = 0; r < 4; ++r) {
                const long moff = (mrow + r) * 1024;
#pragma unroll
                for (int j = 0; j < 4; ++j) {
                    float v = acc[i][j][r];
                    if (act) v = fmaxf(v, 0.f) + 0.125f;
                    dst[moff + colbase + j * 16 + fr] = __float2bfloat16(v);
                }
            }
        }
    } else {
        const long nbase = n0 + wn;
#pragma unroll
        for (int i = 0; i < 4; ++i) {
            const long mrow = m0 + wm + i * 16 + qd * 4;
#pragma unroll
            for (int r = 0; r < 4; ++r) {
                const long moff = (mrow + r) * 1024;
#pragma unroll
                for (int j = 0; j < 4; ++j)
                    outf[moff + nbase + j * 16 + fr] =
                        acc[i][j][r] + bias[nbase + j * 16 + fr];
            }
        }
    }
}

// ---------------------------------------------------------------------------
// Phase 2: kv[bh,e,d] partials over n, 14-way split (224 rows each).
// Block = (bb, h-octet, sp); 256 thr = 8 h-sub x (8 e-blk x 4 d-blk).
// Thread: 8e x 16d register tile -> FMA-bound (128 FMA per 6 ds_read_b128).
// kvp written in MFMA-B-FRAGMENT order: [sp][bh][(s2*4+j)*64+lane][jj],
// elem = kv[e = s2*32+(lane>>4)*8+jj][d = j*16+(lane&15)].
// ---------------------------------------------------------------------------
__global__ __launch_bounds__(256)
void kv_partial_kernel(const __hip_bfloat16* __restrict__ kbuf,
                       const __hip_bfloat16* __restrict__ vbuf,
                       float* __restrict__ kvp,    // [14][128][4096] frag-order
                       float* __restrict__ ksump)  // [14][128][64]
{
    __shared__ float kf[8][512];
    __shared__ float vf[8][512];
    const int t   = threadIdx.x;
    const int bid = blockIdx.x;
    const int sp   = bid % 14;
    const int hoct = (bid / 14) & 1;
    const int bb   = bid / 28;
    const long rowstart = (long)bb * 3136 + sp * 224;

    const int hsub = t >> 5;
    const int w    = t & 31;
    const int E    = w >> 2;         // e-block 0..7
    const int Dq   = w & 3;          // d-block 0..3
    const int cb   = hsub * 64;
    const int e0   = cb + E * 8;
    const int d0   = cb + Dq * 16;

    float kvacc[8][16];
#pragma unroll
    for (int i = 0; i < 8; ++i)
#pragma unroll
        for (int j = 0; j < 16; ++j) kvacc[i][j] = 0.f;
    float ksacc[8] = {0, 0, 0, 0, 0, 0, 0, 0};

    for (int it = 0; it < 28; ++it) {
        __syncthreads();
#pragma unroll
        for (int i = 0; i < 4; ++i) {
            const int idx = t + (i << 8);            // 0..1023
            const int rr  = (idx >> 6) & 7;
            const int c   = idx & 63;
            const long grow = rowstart + it * 8 + rr;
            const __hip_bfloat16* srcp =
                ((idx < 512) ? kbuf : vbuf) + grow * 1024 + hoct * 512 + c * 8;
            bf16x8 v8 = *(const bf16x8*)srcp;
            float* dstp = (idx < 512) ? &kf[rr][c * 8] : &vf[rr][c * 8];
#pragma unroll
            for (int jj = 0; jj < 8; ++jj)
                dstp[jj] = bf2f((unsigned short)v8[jj]);
        }
        __syncthreads();
#pragma unroll
        for (int r = 0; r < 8; ++r) {
            float ke[8], vd[16];
#pragma unroll
            for (int i = 0; i < 8; ++i)  ke[i] = kf[r][e0 + i];
#pragma unroll
            for (int j = 0; j < 16; ++j) vd[j] = vf[r][d0 + j];
#pragma unroll
            for (int i = 0; i < 8; ++i) {
                ksacc[i] += ke[i];
#pragma unroll
                for (int j = 0; j < 16; ++j)
                    kvacc[i][j] += ke[i] * vd[j];
            }
        }
    }

    const int bh = bb * 16 + hoct * 8 + hsub;
    const int s2 = E >> 2, qd = E & 3;
    float* outp = kvp + ((long)sp * 128 + bh) * 4096 + ((s2 * 4 + Dq) * 64 + qd * 16) * 8;
#pragma unroll
    for (int fr = 0; fr < 16; ++fr)
#pragma unroll
        for (int jj = 0; jj < 8; ++jj)
            outp[fr * 8 + jj] = kvacc[jj][fr];
    if (Dq == 0) {
#pragma unroll
        for (int i = 0; i < 8; ++i)
            ksump[sp * 8192 + bh * 64 + E * 8 + i] = ksacc[i];
    }
}

// ---------------------------------------------------------------------------
// Phase 2b: reduce 14 partials; kv -> bf16 frag-order, ksum -> fp32.
// ---------------------------------------------------------------------------
__global__ __launch_bounds__(256)
void reduce_kv_kernel(const float* __restrict__ kvp, const float* __restrict__ ksump,
                      unsigned short* __restrict__ kvb, float* __restrict__ ksum)
{
    const int idx = blockIdx.x * 256 + threadIdx.x;
    if (idx < 128 * 4096) {
        float a = 0.f;
#pragma unroll
        for (int s = 0; s < 14; ++s) a += kvp[(long)s * 128 * 4096 + idx];
        kvb[idx] = f2bf(a);
    } else {
        const int j = idx - 128 * 4096;
        if (j < 128 * 64) {
            float a = 0.f;
#pragma unroll
            for (int s = 0; s < 14; ++s) a += ksump[s * 8192 + j];
            ksum[j] = a;
        }
    }
}

// ---------------------------------------------------------------------------
// Phase 3: out2 = (q @ kv) * z via MFMA (K=64). Block = 64 rows x 64 d, one h.
// kv read as pre-packed B-fragments (one coalesced dwordx4 per frag).
// ---------------------------------------------------------------------------
__global__ __launch_bounds__(256)
void attn_out_kernel(const __hip_bfloat16* __restrict__ qbuf,
                     const unsigned short* __restrict__ kvb,  // [128][4096] frag-order
                     const float* __restrict__ ksum,          // [128][64]
                     __hip_bfloat16* __restrict__ out2)
{
    __shared__ __attribute__((aligned(16))) unsigned short qs[64][64];
    __shared__ float kss[64];
    __shared__ float zs[64];
    const int t   = threadIdx.x;
    const int bid = blockIdx.x;
    const int mc  = bid % 49;
    const int h   = (bid / 49) & 15;
    const int bb  = bid / 784;
    const long bh = bb * 16 + h;
    const long mbase = (long)bb * 3136 + mc * 64;

#pragma unroll
    for (int i = 0; i < 2; ++i) {
        const int idx = t + (i << 8);
        const int row = idx >> 3;
        const int c   = idx & 7;
        *(bf16x8*)&qs[row][c * 8] =
            *(const bf16x8*)(qbuf + (mbase + row) * 1024 + h * 64 + c * 8);
    }
    if (t < 64) kss[t] = ksum[bh * 64 + t];
    __syncthreads();
    if (t < 64) {
        float p = 0.f;
#pragma unroll
        for (int e = 0; e < 64; ++e) p += bf2f(qs[t][e]) * kss[e];
        zs[t] = 1.f / (p + 1e-6f);
    }
    __syncthreads();

    const int lane = t & 63;
    const int wv   = t >> 6;
    const int fr   = lane & 15;
    const int qd   = lane >> 4;

    bf16x8 bfv[2][4];
#pragma unroll
    for (int s2 = 0; s2 < 2; ++s2)
#pragma unroll
        for (int j = 0; j < 4; ++j)
            bfv[s2][j] = *(const bf16x8*)(kvb + bh * 4096 + ((s2 * 4 + j) * 64 + lane) * 8);

    const bf16x8 af0 = *(const bf16x8*)&qs[wv * 16 + fr][qd * 8];
    const bf16x8 af1 = *(const bf16x8*)&qs[wv * 16 + fr][32 + qd * 8];

    float zr[4];
#pragma unroll
    for (int r = 0; r < 4; ++r) zr[r] = zs[wv * 16 + qd * 4 + r];

#pragma unroll
    for (int j = 0; j < 4; ++j) {
        f32x4 acc = {};
        acc = __builtin_amdgcn_mfma_f32_16x16x32_bf16(af0, bfv[0][j], acc, 0, 0, 0);
        acc = __builtin_amdgcn_mfma_f32_16x16x32_bf16(af1, bfv[1][j], acc, 0, 0, 0);
#pragma unroll
        for (int r = 0; r < 4; ++r) {
            const long m = mbase + wv * 16 + qd * 4 + r;
            out2[m * 1024 + h * 64 + j * 16 + fr] = __float2bfloat16(acc[r] * zr[r]);
        }
    }
}

// ---------------------------------------------------------------------------
extern "C" void kernel_launch(void* const* d_in, const int* in_sizes, int n_in,
                              void* d_out, int out_size, void* d_ws, size_t ws_size,
                              hipStream_t stream)
{
    const float* x      = (const float*)d_in[0];
    const float* w_qkv  = (const float*)d_in[1];
    const float* w_proj = (const float*)d_in[2];
    const float* b_proj = (const float*)d_in[3];
    float* out = (float*)d_out;

    const long M = 25088;  // 128*196
    char* ws = (char*)d_ws;
    size_t off = 0;
    auto alloc = [&](size_t bytes) {
        char* p = ws + off;
        off += (bytes + 255) & ~(size_t)255;
        return p;
    };
    // ws (~112 MB): xb region reused as kvp/ksump after QKV GEMM consumes xb.
    char* xb_region = alloc(M * 1024 * 2);                 // 51.4 MB
    unsigned short* xb     = (unsigned short*)xb_region;
    float*          kvp    = (float*)xb_region;            // alias: 14*128*4096*4 = 29.4 MB
    float*          ksump  = (float*)(xb_region + (size_t)14 * 128 * 4096 * 4);
    unsigned short* wqkvb  = (unsigned short*)alloc((size_t)3072 * 1024 * 2);
    unsigned short* wprojb = (unsigned short*)alloc((size_t)1024 * 1024 * 2);
    unsigned short* vbuf   = (unsigned short*)alloc(M * 1024 * 2);
    unsigned short* kvb    = (unsigned short*)alloc((size_t)128 * 4096 * 2);
    float*          ksumr  = (float*)alloc((size_t)128 * 64 * 4);
    // d_out (103 MB) hosts qbuf+kbuf (both dead before final GEMM writes it).
    __hip_bfloat16* qbuf = (__hip_bfloat16*)d_out;
    __hip_bfloat16* kbuf = qbuf + M * 1024;
    __hip_bfloat16* out2 = (__hip_bfloat16*)vbuf;  // v dead after phase 2

    // 0) bf16 conversions (element counts all divisible by 2048)
    cvt_kernel<<<12544, 256, 0, stream>>>(x, xb);
    cvt_kernel<<<1536, 256, 0, stream>>>(w_qkv, wqkvb);
    cvt_kernel<<<512, 256, 0, stream>>>(w_proj, wprojb);
    // 1) qkv GEMM, fused relu+0.125, scatter q/k/v
    gemm_bt_kernel<0><<<196 * 24, 256, 0, stream>>>(
        xb, wqkvb, qbuf, kbuf, (__hip_bfloat16*)vbuf, nullptr, nullptr);
    // 2) kv/ksum partials (frag-ordered)
    kv_partial_kernel<<<224, 256, 0, stream>>>(kbuf, (const __hip_bfloat16*)vbuf, kvp, ksump);
    // 2b) reduce -> kvb bf16 + ksum fp32
    reduce_kv_kernel<<<2080, 256, 0, stream>>>(kvp, ksump, kvb, ksumr);
    // 3) out2 = (q @ kv) * z   (MFMA, K=64)
    attn_out_kernel<<<8 * 16 * 49, 256, 0, stream>>>(qbuf, kvb, ksumr, out2);
    // 4) out = out2 @ w_proj^T + bias
    gemm_bt_kernel<1><<<196 * 8, 256, 0, stream>>>(
        (const unsigned short*)out2, wprojb, nullptr, nullptr, nullptr, out, b_proj);
}